// Round 15
// baseline (1001.076 us; speedup 1.0000x reference)
//
#include <hip/hip_runtime.h>
#include <math.h>

// Problem constants (B=16, N=2048, TF=7, D=512, H=8, dh=64, Lyr=2, T=96)
constexpr int kB  = 16;
constexpr int kN  = 2048;
constexpr int kTF = 7;
constexpr int kD  = 512;
constexpr int kT  = 96;

typedef unsigned short u16;
typedef unsigned int   u32;
typedef unsigned long long u64;
typedef _Float16 f16;
typedef float f32x4 __attribute__((ext_vector_type(4)));
typedef short s16x4 __attribute__((ext_vector_type(4)));
typedef short s16x8 __attribute__((ext_vector_type(8)));
typedef _Float16 f16x8 __attribute__((ext_vector_type(8)));

__device__ __forceinline__ float sigf_fast(float x) { return 1.0f / (1.0f + __expf(-x)); }
__device__ __forceinline__ float sigf_acc (float x) { return 1.0f / (1.0f + expf(-x)); }

__device__ __forceinline__ u16 f2h(float f) {
  f16 h = (f16)f;
  return __builtin_bit_cast(u16, h);
}
__device__ __forceinline__ float h2f(u16 u) {
  return (float)__builtin_bit_cast(f16, u);
}

// async global->LDS, 16B per lane; lds base must be wave-uniform
__device__ __forceinline__ void gl_lds16(const u16* g, u16* l) {
  __builtin_amdgcn_global_load_lds(
      (const __attribute__((address_space(1))) u32*)g,
      (__attribute__((address_space(3))) u32*)l, 16, 0, 0);
}

// ---------------------------------------------------------------- utilities
__global__ void k_zero(float* p, int n) {
  int i = blockIdx.x * 256 + threadIdx.x;
  if (i < n) p[i] = 0.0f;
}

// fp32 -> fp16 convert (weights)
__global__ void k_wcvt(const float* __restrict__ w, u16* __restrict__ h, int n) {
  int i = blockIdx.x * 256 + threadIdx.x;
  if (i >= n) return;
  h[i] = f2h(w[i]);
}

// xT[b][c][n] = x[b][n][c]
__global__ void k_transpose_x(const float* __restrict__ x, float* __restrict__ xT) {
  int i = blockIdx.x * 256 + threadIdx.x;
  if (i >= kB * kTF * kN) return;
  int n = i & (kN - 1);
  int c = (i >> 11) % kTF;
  int b = i / (kTF * kN);
  xT[i] = x[((long)b * kN + n) * kTF + c];
}

// tgp[l][c][d] = sum_e tg_w[l][c][e] * pout_w[l][e][d];  gbc = tg_b + tg_w @ pout_b
__global__ void k_precompute(const float* __restrict__ tg_w, const float* __restrict__ tg_b,
                             const float* __restrict__ pout_w, const float* __restrict__ pout_b,
                             float* __restrict__ tgp, float* __restrict__ gbc) {
  int lc = blockIdx.x;            // l*7 + c
  int l = lc / 7;
  int tid = threadIdx.x;
  const float* tw = tg_w + lc * kD;
  const float* pw = pout_w + (long)l * kD * kD;
  for (int d = tid; d < kD; d += 256) {
    float acc = 0.0f;
    for (int e = 0; e < kD; ++e) acc = fmaf(tw[e], pw[(long)e * kD + d], acc);
    tgp[lc * kD + d] = acc;
  }
  if (tid == 0) {
    float acc = tg_b[lc];
    const float* pb = pout_b + l * kD;
    for (int e = 0; e < kD; ++e) acc = fmaf(tw[e], pb[e], acc);
    gbc[lc] = acc;
  }
}

// Conv1d(TF->D, k=3, pad=1) -> z as fp16 hi/lo
__global__ __launch_bounds__(256)
void k_embed(const float* __restrict__ x, const float* __restrict__ w,
             const float* __restrict__ bias, u16* __restrict__ Zh, u16* __restrict__ Zl) {
  int n = blockIdx.x * 256 + threadIdx.x;
  int d0 = blockIdx.y * 8;
  int b = blockIdx.z;
  const float* xb = x + (long)b * kN * kTF;
  float xr[21];
#pragma unroll
  for (int k = 0; k < 3; ++k) {
    int nn = n + k - 1;
    bool ok = (nn >= 0) && (nn < kN);
#pragma unroll
    for (int c = 0; c < 7; ++c) xr[k * 7 + c] = ok ? xb[nn * kTF + c] : 0.0f;
  }
  for (int dd = 0; dd < 8; ++dd) {
    int d = d0 + dd;
    const float* wd = w + d * 21;
    float acc = bias[d];
#pragma unroll
    for (int k = 0; k < 3; ++k)
#pragma unroll
      for (int c = 0; c < 7; ++c) acc = fmaf(xr[k * 7 + c], wd[c * 3 + k], acc);
    long idx = ((long)(b * kD + d)) * kN + n;
    u16 hh = f2h(acc);
    Zh[idx] = hh;
    Zl[idx] = f2h(acc - h2f(hh));
  }
}

// -------------------------------------------------- freq_attention
// 512-thread blocks (occupancy fix: 4 blk/CU = 32 waves = ~100%).
// Forward packed FFT (radix-4 passes, one group/thread) + top-4 SQUARED-
// amplitude mask; inverse replaced by DIRECT SYNTHESIS over survivors.
#define AP(i) ((i) + ((i) >> 4))
#define TOP4_INS(key)                                              \
  do { u64 _k = (key);                                             \
    if (_k > t2) {                                                 \
      if (_k > t0)      { t3 = t2; t2 = t1; t1 = t0; t0 = _k; }    \
      else if (_k > t1) { t3 = t2; t2 = t1; t1 = _k; }             \
      else              { t3 = t2; t2 = _k; }                      \
    } else if (_k > t3) { t3 = _k; }                               \
  } while (0)

__global__ __launch_bounds__(512)
void k_fft(u16* __restrict__ zh, u16* __restrict__ zl,
           u16* __restrict__ lsb, float* __restrict__ SLS) {
  __shared__ float2 arr[2176];          // 2048 padded by i>>4
  __shared__ float2 twamp[1025];        // tw[0..1023] aliased with amp[0..2049]
  __shared__ u64   s_top[2][8][4];      // [col][wave][rank]
  __shared__ int   s_cnt[8];
  __shared__ float s_sv[2][4];
  __shared__ int   s_si[2][4];
  __shared__ float s_kth[2];
  __shared__ int   sKa[32], sKb[32];
  __shared__ float sCa[32], sSa[32], sCb[32], sSb[32];
  float* ampf = (float*)twamp;

  const int tid = threadIdx.x;
  const int b  = blockIdx.x >> 8;
  const int dp = blockIdx.x & 255;
  const long rowA = ((long)b * kD + dp * 2) * kN;
  const long rowB = rowA + kN;
  const int n0 = tid * 4;
  const int pbase = (int)(__brev((unsigned)tid) >> 23);   // brev9(tid)

  // ---- vectorized load + recombine + stash + bit-reversed scatter
  s16x4 vh = *(const s16x4*)&zh[rowA + n0];
  s16x4 vl = *(const s16x4*)&zl[rowA + n0];
  s16x4 wh = *(const s16x4*)&zh[rowB + n0];
  s16x4 wl = *(const s16x4*)&zl[rowB + n0];
  float2 stash[4];
#pragma unroll
  for (int j = 0; j < 4; ++j) {
    const int jr[4] = {0, 2, 1, 3};
    float va = h2f((u16)vh[j]) + h2f((u16)vl[j]);
    float vb = h2f((u16)wh[j]) + h2f((u16)wl[j]);
    stash[j] = make_float2(va, vb);
    int p = jr[j] * 512 + pbase;
    arr[AP(p)] = make_float2(va, vb);
  }
  for (int j = tid; j < 1024; j += 512) {
    float sw, cw;
    __sincosf(-6.283185307179586f * (float)j * (1.0f / 2048.0f), &sw, &cw);
    twamp[j] = make_float2(cw, sw);
  }
  __syncthreads();
  // ---- forward FFT: 5 radix-4 passes (one group/thread) + final radix-2
#pragma unroll
  for (int lh = 0; lh <= 8; lh += 2) {
    const int h = 1 << lh;
    const int sh1 = 10 - lh;
    const int sh2 = 9 - lh;
    {
      int g = tid;
      int pos = g & (h - 1);
      int i0 = ((g >> lh) << (lh + 2)) + pos;
      float2 a  = arr[AP(i0)];
      float2 bv = arr[AP(i0 + h)];
      float2 c  = arr[AP(i0 + 2 * h)];
      float2 d  = arr[AP(i0 + 3 * h)];
      float2 w1 = twamp[pos << sh1];
      float2 w2 = twamp[pos << sh2];
      float tbr = w1.x * bv.x - w1.y * bv.y, tbi = w1.x * bv.y + w1.y * bv.x;
      float tdr = w1.x * d.x  - w1.y * d.y,  tdi = w1.x * d.y  + w1.y * d.x;
      float a1r = a.x + tbr, a1i = a.y + tbi;
      float b1r = a.x - tbr, b1i = a.y - tbi;
      float c1r = c.x + tdr, c1i = c.y + tdi;
      float d1r = c.x - tdr, d1i = c.y - tdi;
      float tcr = w2.x * c1r - w2.y * c1i, tci = w2.x * c1i + w2.y * c1r;
      float ter = w2.y * d1r + w2.x * d1i;
      float tei = w2.y * d1i - w2.x * d1r;
      arr[AP(i0)]         = make_float2(a1r + tcr, a1i + tci);
      arr[AP(i0 + 2 * h)] = make_float2(a1r - tcr, a1i - tci);
      arr[AP(i0 + h)]     = make_float2(b1r + ter, b1i + tei);
      arr[AP(i0 + 3 * h)] = make_float2(b1r - ter, b1i - tei);
    }
    __syncthreads();
  }
  // final radix-2 stage (stride 1024); two pairs per thread
  for (int j = tid; j < 1024; j += 512) {
    float2 w = twamp[j];
    float2 a  = arr[AP(j)];
    float2 bv = arr[AP(j + 1024)];
    float tr = w.x * bv.x - w.y * bv.y;
    float ti = w.x * bv.y + w.y * bv.x;
    arr[AP(j + 1024)] = make_float2(a.x - tr, a.y - ti);
    arr[AP(j)]        = make_float2(a.x + tr, a.y + ti);
  }
  __syncthreads();
  // ---- unpack SQUARED amplitudes (overwrites tw region)
  for (int k = tid; k <= 1024; k += 512) {
    float2 V0 = arr[AP(k)];
    float2 V1 = arr[AP((2048 - k) & 2047)];
    float ar = 0.5f * (V0.x + V1.x);
    float ai = 0.5f * (V0.y - V1.y);
    float br = 0.5f * (V0.y + V1.y);
    float bi = 0.5f * (V1.x - V0.x);
    ampf[k]        = ar * ar + ai * ai;
    ampf[1025 + k] = br * br + bi * bi;
  }
  __syncthreads();
  // ---- top-4 per column: single-pass sorted insert + wave shfl merge
#pragma unroll
  for (int col = 0; col < 2; ++col) {
    const float* A = ampf + col * 1025;
    u64 t0 = 0, t1 = 0, t2 = 0, t3 = 0;
    for (int k = tid; k <= 1024; k += 512) {
      u64 key = ((u64)__float_as_uint(A[k]) << 32) | (u32)k;
      TOP4_INS(key);
    }
#pragma unroll
    for (int off = 32; off > 0; off >>= 1) {
      u64 o0 = __shfl_xor(t0, off), o1 = __shfl_xor(t1, off);
      u64 o2 = __shfl_xor(t2, off), o3 = __shfl_xor(t3, off);
      TOP4_INS(o0); TOP4_INS(o1); TOP4_INS(o2); TOP4_INS(o3);
    }
    if ((tid & 63) == 0) {
      int w = tid >> 6;
      s_top[col][w][0] = t0; s_top[col][w][1] = t1;
      s_top[col][w][2] = t2; s_top[col][w][3] = t3;
    }
  }
  __syncthreads();
  if (tid < 2) {
    int col = tid;
    u64 t0 = s_top[col][0][0], t1 = s_top[col][0][1];
    u64 t2 = s_top[col][0][2], t3 = s_top[col][0][3];
    for (int w = 1; w < 8; ++w) {
#pragma unroll
      for (int r = 0; r < 4; ++r) { u64 key = s_top[col][w][r]; TOP4_INS(key); }
    }
    u64 tt[4] = {t0, t1, t2, t3};
#pragma unroll
    for (int r = 0; r < 4; ++r) {
      s_sv[col][r] = __uint_as_float((u32)(tt[r] >> 32));
      s_si[col][r] = (int)(tt[r] & 0xffffffffu);
    }
    s_kth[col] = __uint_as_float((u32)(tt[3] >> 32));
  }
  __syncthreads();
  const float kthA = s_kth[0], kthB = s_kth[1];
  // ---- survivor counts (deterministic)
  int cA = 0, cB = 0;
  for (int k = tid; k <= 1024; k += 512) {
    if (ampf[k] >= kthA) ++cA;
    if (ampf[1025 + k] >= kthB) ++cB;
  }
  int pc = cA | (cB << 16);
#pragma unroll
  for (int off = 32; off > 0; off >>= 1) pc += __shfl_xor(pc, off);
  if ((tid & 63) == 0) s_cnt[tid >> 6] = pc;
  __syncthreads();
  int tot = 0;
#pragma unroll
  for (int w = 0; w < 8; ++w) tot += s_cnt[w];
  const int nA = tot & 0xffff, nB = tot >> 16;
  // ---- gather survivor coefficients (fast path: exactly the top-4)
  if (nA == 4) {
    if (tid < 4) {
      int k = s_si[0][tid];
      float2 V0 = arr[AP(k)];
      float2 V1 = arr[AP((2048 - k) & 2047)];
      float w = (k == 0 || k == 1024) ? 1.0f : 2.0f;
      sKa[tid] = k;
      sCa[tid] = w * 0.5f * (V0.x + V1.x);
      sSa[tid] = w * 0.5f * (V0.y - V1.y);
    }
  } else if (tid == 0) {
    int c = 0;
    for (int k = 0; k <= 1024 && c < 32; ++k) {
      if (ampf[k] >= kthA) {
        float2 V0 = arr[AP(k)];
        float2 V1 = arr[AP((2048 - k) & 2047)];
        float w = (k == 0 || k == 1024) ? 1.0f : 2.0f;
        sKa[c] = k;
        sCa[c] = w * 0.5f * (V0.x + V1.x);
        sSa[c] = w * 0.5f * (V0.y - V1.y);
        ++c;
      }
    }
  }
  if (nB == 4) {
    if (tid >= 64 && tid < 68) {
      int r = tid - 64;
      int k = s_si[1][r];
      float2 V0 = arr[AP(k)];
      float2 V1 = arr[AP((2048 - k) & 2047)];
      float w = (k == 0 || k == 1024) ? 1.0f : 2.0f;
      sKb[r] = k;
      sCb[r] = w * 0.5f * (V0.y + V1.y);
      sSb[r] = w * 0.5f * (V1.x - V0.x);
    }
  } else if (tid == 64) {
    int c = 0;
    for (int k = 0; k <= 1024 && c < 32; ++k) {
      if (ampf[1025 + k] >= kthB) {
        float2 V0 = arr[AP(k)];
        float2 V1 = arr[AP((2048 - k) & 2047)];
        float w = (k == 0 || k == 1024) ? 1.0f : 2.0f;
        sKb[c] = k;
        sCb[c] = w * 0.5f * (V0.y + V1.y);
        sSb[c] = w * 0.5f * (V1.x - V0.x);
        ++c;
      }
    }
  }
  __syncthreads();
  // ---- direct synthesis: ls[n] = (1/N) sum w_k (ar cos - ai sin), theta exact
  const int nAc = (nA < 32) ? nA : 32;
  const int nBc = (nB < 32) ? nB : 32;
  float synA[4] = {0, 0, 0, 0};
  float synB[4] = {0, 0, 0, 0};
  const float w2pi = 6.283185307179586f * (1.0f / 2048.0f);
  for (int s = 0; s < nAc; ++s) {
    int k = sKa[s];
    float cr = sCa[s], ci = sSa[s];
    float c0, s0, cs, ss;
    __sincosf(w2pi * (float)((k * n0) & 2047), &s0, &c0);
    __sincosf(w2pi * (float)k, &ss, &cs);
#pragma unroll
    for (int j = 0; j < 4; ++j) {
      synA[j] += cr * c0 - ci * s0;
      float nc = c0 * cs - s0 * ss;
      s0 = s0 * cs + c0 * ss;
      c0 = nc;
    }
  }
  for (int s = 0; s < nBc; ++s) {
    int k = sKb[s];
    float cr = sCb[s], ci = sSb[s];
    float c0, s0, cs, ss;
    __sincosf(w2pi * (float)((k * n0) & 2047), &s0, &c0);
    __sincosf(w2pi * (float)k, &ss, &cs);
#pragma unroll
    for (int j = 0; j < 4; ++j) {
      synB[j] += cr * c0 - ci * s0;
      float nc = c0 * cs - s0 * ss;
      s0 = s0 * cs + c0 * ss;
      c0 = nc;
    }
  }
  // ---- vectorized writeback: ls (fp16), z -= ls (h/l), SLS (fp32)
  const float inv = 1.0f / 2048.0f;
  s16x4 oh_a, ol_a, oh_b, ol_b, os_a, os_b;
  float la4[4], lb4[4];
#pragma unroll
  for (int j = 0; j < 4; ++j) {
    float la = synA[j] * inv, lb = synB[j] * inv;
    la4[j] = la; lb4[j] = lb;
    os_a[j] = (short)f2h(la);
    os_b[j] = (short)f2h(lb);
    float za = stash[j].x - la, zb = stash[j].y - lb;
    u16 ha = f2h(za), hb = f2h(zb);
    oh_a[j] = (short)ha; ol_a[j] = (short)f2h(za - h2f(ha));
    oh_b[j] = (short)hb; ol_b[j] = (short)f2h(zb - h2f(hb));
  }
  *(s16x4*)&lsb[rowA + n0] = os_a;
  *(s16x4*)&lsb[rowB + n0] = os_b;
  *(s16x4*)&zh[rowA + n0] = oh_a;
  *(s16x4*)&zl[rowA + n0] = ol_a;
  *(s16x4*)&zh[rowB + n0] = oh_b;
  *(s16x4*)&zl[rowB + n0] = ol_b;
  if (n0 < kT) {
    float* s0p = &SLS[((long)(b * kD + dp * 2)) * kT + n0];
    float* s1p = &SLS[((long)(b * kD + dp * 2 + 1)) * kT + n0];
#pragma unroll
    for (int j = 0; j < 4; ++j) { s0p[j] += la4[j]; s1p[j] += lb4[j]; }
  }
}

// ==================================================================== MFMA GEMM
// C[M,N] = W[M,K] x Act[K,N] per batch. FP16 single-product MFMA.
// 256 threads, 4 waves (2x2), tile 128x128, BK=32, 64-K macro-iterations.
// CROSS-ITERATION 2-PHASE PIPELINE: 2 LDS buffer sets (72 KB, 2 blk/CU);
// stage(t+1) issued BEFORE compute(t); ONE barrier per 64-K iteration.
// AW=1: A pre-converted fp16 (gl_lds16 + XOR-swizzled source).
// EP: 0 = fp32 store; 1 = z(h/l) -= (acc+bias); 2 = fp16 sigmoid; 3 = fp16 store.
// SK=1: blockIdx.z encodes (khalf = z>>4, batch = z&15), K-half offset 1024.
template<int EP, int AW, int SK>
__global__ __launch_bounds__(256)
void k_mgemm(const void* __restrict__ Ag, int lda,
             const u16* __restrict__ Bh, int ldb, long strideB,
             void* __restrict__ Cgv, u16* __restrict__ Czh, u16* __restrict__ Czl,
             int ldc, long strideC,
             const float* __restrict__ bias, int K) {
  __shared__ u16 sA[2][2][128 * 32];
  __shared__ u16 sB[2][2][128 * 40];

  const int tid = threadIdx.x;
  const int bx = blockIdx.x, by = blockIdx.y, bz = blockIdx.z;
  const int batch = SK ? (bz & 15) : bz;
  const int kofs  = SK ? ((bz >> 4) * 1024) : 0;
  const int lane = tid & 63;
  const int wid  = tid >> 6;
  const int wm = wid >> 1, wn = wid & 1;
  const int l15 = lane & 15, lk = lane >> 4;

  const u16* Bbase = Bh + (size_t)batch * strideB + (size_t)kofs * ldb + bx * 128;
  const u16* Abase = (const u16*)Ag + kofs;
  const float* Afb = (const float*)Ag + kofs;

  f32x4 acc[4][4];
#pragma unroll
  for (int i = 0; i < 4; ++i)
#pragma unroll
    for (int j = 0; j < 4; ++j) acc[i][j] = (f32x4)(0.0f);

  const int kq = tid >> 5, nb = tid & 31, n0 = nb * 4;
  s16x4 br[2][4];

#define STAGEA(bf, half, k0)                                                  \
  do {                                                                        \
    if (AW) {                                                                 \
      _Pragma("unroll")                                                       \
      for (int c = 0; c < 2; ++c) {                                           \
        int L = wid * 128 + c * 64 + lane;                                    \
        int m = L >> 2, s = L & 3;                                            \
        int klog = ((s ^ ((m >> 1) & 3)) << 3);                               \
        size_t srco = (size_t)(by * 128 + m) * lda + (k0) + klog;             \
        gl_lds16(Abase + srco,                                                \
                 &sA[bf][half][(size_t)(wid * 128 + c * 64) * 8]);            \
      }                                                                       \
    } else {                                                                  \
      _Pragma("unroll")                                                       \
      for (int it = 0; it < 2; ++it) {                                        \
        int m = it * 64 + (tid >> 2), s = tid & 3;                            \
        const float* ap = Afb + (size_t)(by * 128 + m) * lda + (k0) + s * 8;  \
        f32x4 v0 = *(const f32x4*)ap;                                         \
        f32x4 v1 = *(const f32x4*)(ap + 4);                                   \
        float fv[8] = {v0[0], v0[1], v0[2], v0[3],                            \
                       v1[0], v1[1], v1[2], v1[3]};                           \
        u32 hh[8];                                                            \
        _Pragma("unroll")                                                     \
        for (int e = 0; e < 8; ++e) hh[e] = f2h(fv[e]);                       \
        int so = ((s ^ ((m >> 1) & 3)) << 3);                                 \
        uint4 vp = make_uint4(hh[0] | (hh[1] << 16), hh[2] | (hh[3] << 16),   \
                              hh[4] | (hh[5] << 16), hh[6] | (hh[7] << 16));  \
        *(uint4*)&sA[bf][half][m * 32 + so] = vp;                             \
      }                                                                       \
    }                                                                         \
  } while (0)

#define LOADB(half, k0)                                                       \
  do {                                                                        \
    const u16* bp = Bbase + (size_t)((k0) + kq * 4) * ldb + n0;               \
    br[half][0] = *(const s16x4*)bp;                                          \
    br[half][1] = *(const s16x4*)(bp + ldb);                                  \
    br[half][2] = *(const s16x4*)(bp + 2 * (size_t)ldb);                      \
    br[half][3] = *(const s16x4*)(bp + 3 * (size_t)ldb);                      \
  } while (0)

#define WRITEB(bf, half)                                                      \
  do {                                                                        \
    _Pragma("unroll")                                                         \
    for (int i = 0; i < 4; ++i) {                                             \
      int n = n0 + i;                                                         \
      int so = (((kq >> 1) ^ ((n >> 2) & 3)) << 3) + (kq & 1) * 4;            \
      *(uint2*)&sB[bf][half][n * 40 + so] = make_uint2(                       \
          (u32)(u16)br[half][0][i] | ((u32)(u16)br[half][1][i] << 16),        \
          (u32)(u16)br[half][2][i] | ((u32)(u16)br[half][3][i] << 16));       \
    }                                                                         \
  } while (0)

#define COMPUTE(bf, half)                                                     \
  do {                                                                        \
    f16x8 bhf[4];                                                             \
    _Pragma("unroll")                                                         \
    for (int ni = 0; ni < 4; ++ni) {                                          \
      int row = wn * 64 + ni * 16 + l15;                                      \
      int so = ((lk ^ ((row >> 2) & 3)) << 3);                                \
      bhf[ni] = *(const f16x8*)&sB[bf][half][row * 40 + so];                  \
    }                                                                         \
    _Pragma("unroll")                                                         \
    for (int mi = 0; mi < 4; ++mi) {                                          \
      int row = wm * 64 + mi * 16 + l15;                                      \
      int so = ((lk ^ ((row >> 1) & 3)) << 3);                                \
      f16x8 ah = *(const f16x8*)&sA[bf][half][row * 32 + so];                 \
      _Pragma("unroll")                                                       \
      for (int ni = 0; ni < 4; ++ni)                                          \
        acc[mi][ni] = __builtin_amdgcn_mfma_f32_16x16x32_f16(                 \
            ah, bhf[ni], acc[mi][ni], 0, 0, 0);                               \
    }                                                                         \
  } while (0)

  // prologue: stage iteration 0 into set 0
  STAGEA(0, 0, 0);
  STAGEA(0, 1, 32);
  LOADB(0, 0);
  LOADB(1, 32);
  WRITEB(0, 0);
  WRITEB(0, 1);
  __syncthreads();

  const int NT = K >> 6;
  for (int t = 0; t < NT; ++t) {
    const int cur = t & 1, nxt = cur ^ 1;
    const int kn = (t + 1) * 64;
    if (t + 1 < NT) {
      STAGEA(nxt, 0, kn);          // gl_lds in flight during compute
      STAGEA(nxt, 1, kn + 32);
      LOADB(0, kn);                // B loads in flight during compute
      LOADB(1, kn + 32);
    }
    COMPUTE(cur, 0);
    COMPUTE(cur, 1);
    if (t + 1 < NT) {
      WRITEB(nxt, 0);
      WRITEB(nxt, 1);
    }
    __syncthreads();               // single drain+barrier per 64-K iteration
  }
#undef STAGEA
#undef LOADB
#undef WRITEB
#undef COMPUTE

  // ---- epilogue (C/D: col = lane&15, row = (lane>>4)*4 + reg)
  const float bmul = (SK && (bz >> 4)) ? 0.0f : 1.0f;
  float* Cf = (float*)Cgv + (size_t)bz * strideC;
  u16*   Ch = (u16*)Cgv + (size_t)bz * strideC;
  u16*   Zph = Czh ? Czh + (size_t)bz * strideC : nullptr;
  u16*   Zpl = Czl ? Czl + (size_t)bz * strideC : nullptr;
#pragma unroll
  for (int mi = 0; mi < 4; ++mi) {
    int row0 = by * 128 + wm * 64 + mi * 16 + lk * 4;
    float bs[4];
#pragma unroll
    for (int r = 0; r < 4; ++r) bs[r] = bias[row0 + r] * bmul;
#pragma unroll
    for (int ni = 0; ni < 4; ++ni) {
      int col = bx * 128 + wn * 64 + ni * 16 + l15;
#pragma unroll
      for (int r = 0; r < 4; ++r) {
        float v = acc[mi][ni][r] + bs[r];
        size_t off = (size_t)(row0 + r) * ldc + col;
        if (EP == 0) {
          Cf[off] = v;
        } else if (EP == 1) {
          float zv = h2f(Zph[off]) + h2f(Zpl[off]);
          float nv = zv - v;
          u16 hh = f2h(nv);
          Zph[off] = hh;
          Zpl[off] = f2h(nv - h2f(hh));
        } else if (EP == 2) {
          Ch[off] = f2h(sigf_fast(v));
        } else {
          Ch[off] = f2h(v);
        }
      }
    }
  }
}

// ------------------------------------- 7-channel GEMM, 4-way d-split
// HL=1: fp16 rows [b*512][4096] (h at offset 0); HL=2: fp16 [b*512][2048]
template<int HL>
__global__ __launch_bounds__(256)
void k_gemm7v(const float* __restrict__ W, const float* __restrict__ bias,
              const void* __restrict__ in, float* __restrict__ out) {
  __shared__ float Ws[7 * kD];
  __shared__ float red[4][7][64];
  int tid = threadIdx.x;
  for (int i = tid; i < 7 * kD; i += 256) Ws[i] = W[i];
  __syncthreads();
  int nl = tid & 63, dg = tid >> 6;
  int n = blockIdx.x * 64 + nl;
  int b = blockIdx.y;
  float acc[7] = {0, 0, 0, 0, 0, 0, 0};
  if (HL == 1) {
    const u16* ph = (const u16*)in + ((long)b * kD) * 4096 + n;
    for (int d = dg * 128; d < dg * 128 + 128; ++d) {
      float v = h2f(ph[(long)d * 4096]);
#pragma unroll
      for (int c = 0; c < 7; ++c) acc[c] = fmaf(Ws[c * kD + d], v, acc[c]);
    }
  } else {
    const u16* ph = (const u16*)in + ((long)b * kD) * 2048 + n;
    for (int d = dg * 128; d < dg * 128 + 128; ++d) {
      float v = h2f(ph[(long)d * 2048]);
#pragma unroll
      for (int c = 0; c < 7; ++c) acc[c] = fmaf(Ws[c * kD + d], v, acc[c]);
    }
  }
#pragma unroll
  for (int c = 0; c < 7; ++c) red[dg][c][nl] = acc[c];
  __syncthreads();
  if (dg == 0) {
#pragma unroll
    for (int c = 0; c < 7; ++c) {
      float t = red[0][c][nl] + red[1][c][nl] + red[2][c][nl] + red[3][c][nl] + bias[c];
      out[((long)b * kTF + c) * kN + n] = t;
    }
  }
}

// ------------------------------------- mhesa EMA-of-diffs scan
// in/out: u16 rows [row][4096], fp16 h in first 2048 slots (in-place); + GLlast
__global__ __launch_bounds__(64)
void k_scan_mhesa(u16* __restrict__ buf, const float* __restrict__ alpha_raw,
                  const float* __restrict__ init_st, int layer, float* __restrict__ GLlast) {
  int row = blockIdx.x;                // b*512 + d
  int d = row & (kD - 1);
  int h = d >> 6, j = d & 63;
  int lane = threadIdx.x;
  float a = sigf_acc(alpha_raw[layer * 8 + h]);
  float c = 1.0f - a;
  float init = init_st[(layer * 8 + h) * 64 + j];
  long base = (long)row * 4096 + lane * 32;
  float x[32];
  {
    s16x8 r0 = *(const s16x8*)&buf[base];
    s16x8 r1 = *(const s16x8*)&buf[base + 8];
    s16x8 r2 = *(const s16x8*)&buf[base + 16];
    s16x8 r3 = *(const s16x8*)&buf[base + 24];
#pragma unroll
    for (int m = 0; m < 8; ++m) {
      x[m]      = h2f((u16)r0[m]);
      x[m + 8]  = h2f((u16)r1[m]);
      x[m + 16] = h2f((u16)r2[m]);
      x[m + 24] = h2f((u16)r3[m]);
    }
  }
  float prev = __shfl_up(x[31], 1);
  if (lane == 0) prev = init;
  float p[32];
  float pp = 0.0f;
#pragma unroll
  for (int m = 0; m < 32; ++m) {
    float u = a * (x[m] - prev);
    prev = x[m];
    pp = fmaf(c, pp, u);
    p[m] = pp;
  }
  float c2 = c * c, c4 = c2 * c2, c8 = c4 * c4, c16 = c8 * c8;
  float C_ = c16 * c16, U_ = pp;
#pragma unroll
  for (int off = 1; off < 64; off <<= 1) {
    float Cp = __shfl_up(C_, off);
    float Up = __shfl_up(U_, off);
    if (lane >= off) { U_ = fmaf(C_, Up, U_); C_ = C_ * Cp; }
  }
  float Uex = __shfl_up(U_, 1);
  float Cex = __shfl_up(C_, 1);
  if (lane == 0) { Uex = 0.0f; Cex = 1.0f; }
  float yin = fmaf(Cex, init, Uex);
  float pw = c;
  float ylast = 0.0f;
  s16x8 o[4];
#pragma unroll
  for (int m = 0; m < 32; ++m) {
    float y = fmaf(pw, yin, p[m]);
    o[m >> 3][m & 7] = (short)f2h(y);
    pw *= c;
    ylast = y;
  }
  *(s16x8*)&buf[base]      = o[0];
  *(s16x8*)&buf[base + 8]  = o[1];
  *(s16x8*)&buf[base + 16] = o[2];
  *(s16x8*)&buf[base + 24] = o[3];
  if (lane == 63) GLlast[row] = ylast;
}

// ------------------------------------- level scan: y = (1-a)y + a(x-s) + g, init 0
__global__ __launch_bounds__(64)
void k_scan_level(const float* __restrict__ xin, const float* __restrict__ sea,
                  const float* __restrict__ gro, float* __restrict__ xout,
                  const float* __restrict__ lv_alpha, int layer) {
  int row = blockIdx.x;                // b*7 + c
  int lane = threadIdx.x;
  float a = sigf_acc(lv_alpha[layer]);
  float c = 1.0f - a;
  long base = (long)row * kN + lane * 32;
  float p[32];
  float pp = 0.0f;
#pragma unroll
  for (int m = 0; m < 32; ++m) {
    float u = fmaf(a, xin[base + m] - sea[base + m], gro[base + m]);
    pp = fmaf(c, pp, u);
    p[m] = pp;
  }
  float c2 = c * c, c4 = c2 * c2, c8 = c4 * c4, c16 = c8 * c8;
  float C_ = c16 * c16, U_ = pp;
#pragma unroll
  for (int off = 1; off < 64; off <<= 1) {
    float Cp = __shfl_up(C_, off);
    float Up = __shfl_up(U_, off);
    if (lane >= off) { U_ = fmaf(C_, Up, U_); C_ = C_ * Cp; }
  }
  float Uex = __shfl_up(U_, 1);
  if (lane == 0) Uex = 0.0f;
  float yin = Uex;
  float pw = c;
#pragma unroll
  for (int m = 0; m < 32; ++m) {
    xout[base + m] = fmaf(pw, yin, p[m]);
    pw *= c;
  }
}

// ------------------------------------- GL[b,e] += pout(scan_last); grid(16,8)
__global__ __launch_bounds__(256)
void k_gl(const float* __restrict__ GLlast, const float* __restrict__ pw,
          const float* __restrict__ pb, float* __restrict__ GL) {
  __shared__ float sl[kD];
  __shared__ float red[4][64];
  int b = blockIdx.x, tid = threadIdx.x;
  for (int d = tid; d < kD; d += 256) sl[d] = GLlast[b * kD + d];
  __syncthreads();
  int e0 = blockIdx.y * 64;
  int el = tid & 63, kg = tid >> 6;
  float acc = 0.0f;
  const float* pwe = pw + (long)(e0 + el) * kD + kg * 128;
  const float* slp = sl + kg * 128;
  for (int d = 0; d < 128; ++d) acc = fmaf(pwe[d], slp[d], acc);
  red[kg][el] = acc;
  __syncthreads();
  if (kg == 0) {
    float t = red[0][el] + red[1][el] + red[2][el] + red[3][el] + pb[e0 + el];
    GL[b * kD + e0 + el] += t;
  }
}

// ------------------------------------- LayerNorm (z fp16 hi/lo, add fp16), 2-stage
__global__ __launch_bounds__(256)
void k_ln_part(const u16* __restrict__ zh, const u16* __restrict__ zl,
               const u16* __restrict__ a0, const u16* __restrict__ a1,
               float* __restrict__ part, int ncols, int n0) {
  __shared__ float sh1[4][64], sh2[4][64];
  int nperb = ncols >> 6;
  int b = blockIdx.x / nperb, nblk = blockIdx.x % nperb;
  int nl = threadIdx.x & 63;
  int dg = threadIdx.x >> 6;
  int n = nblk * 64 + nl;
  int d0 = blockIdx.y * 64 + dg * 16;
  const u16* zp = zh + (long)b * kD * kN + n0 + n;
  const u16* zq = zl + (long)b * kD * kN + n0 + n;
  const u16* p0 = a0 ? a0 + (long)b * kD * ncols + n : nullptr;
  const u16* p1 = a1 ? a1 + (long)b * kD * ncols + n : nullptr;
  float s1 = 0.0f, s2 = 0.0f;
#pragma unroll
  for (int dd = 0; dd < 16; ++dd) {
    int d = d0 + dd;
    float v = h2f(zp[(long)d * kN]) + h2f(zq[(long)d * kN]);
    if (p0) v += h2f(p0[(long)d * ncols]);
    if (p1) v += h2f(p1[(long)d * ncols]);
    s1 += v; s2 += v * v;
  }
  sh1[dg][nl] = s1; sh2[dg][nl] = s2;
  __syncthreads();
  if (dg == 0) {
    float t1 = sh1[0][nl] + sh1[1][nl] + sh1[2][nl] + sh1[3][nl];
    float t2 = sh2[0][nl] + sh2[1][nl] + sh2[2][nl] + sh2[3][nl];
    long pi = ((long)blockIdx.y * kB * ncols + (long)b * ncols + n) * 2;
    part[pi] = t1; part[pi + 1] = t2;
  }
}

__global__ __launch_bounds__(256)
void k_ln_apply2(u16* __restrict__ zh, u16* __restrict__ zl,
                 const u16* __restrict__ a0, const u16* __restrict__ a1,
                 const float* __restrict__ part,
                 const float* __restrict__ g, const float* __restrict__ bb,
                 int ncols, int n0) {
  __shared__ float smu[64], srs[64];
  int nperb = ncols >> 6;
  int b = blockIdx.x / nperb, nblk = blockIdx.x % nperb;
  int nl = threadIdx.x & 63;
  int dg = threadIdx.x >> 6;
  int n = nblk * 64 + nl;
  if (dg == 0) {
    float t1 = 0.0f, t2 = 0.0f;
#pragma unroll
    for (int s = 0; s < 8; ++s) {
      long pi = ((long)s * kB * ncols + (long)b * ncols + n) * 2;
      t1 += part[pi]; t2 += part[pi + 1];
    }
    float m = t1 * (1.0f / kD);
    float var = t2 * (1.0f / kD) - m * m;
    smu[nl] = m;
    srs[nl] = rsqrtf(var + 1e-5f);
  }
  __syncthreads();
  float m = smu[nl], r = srs[nl];
  int d0 = blockIdx.y * 64 + dg * 16;
  u16* zp = zh + (long)b * kD * kN + n0 + n;
  u16* zq = zl + (long)b * kD * kN + n0 + n;
  const u16* p0 = a0 ? a0 + (long)b * kD * ncols + n : nullptr;
  const u16* p1 = a1 ? a1 + (long)b * kD * ncols + n : nullptr;
#pragma unroll
  for (int dd = 0; dd < 16; ++dd) {
    int d = d0 + dd;
    float v = h2f(zp[(long)d * kN]) + h2f(zq[(long)d * kN]);
    if (p0) v += h2f(p0[(long)d * ncols]);
    if (p1) v += h2f(p1[(long)d * ncols]);
    float nv = (v - m) * r * g[d] + bb[d];
    u16 hh = f2h(nv);
    zp[(long)d * kN] = hh;
    zq[(long)d * kN] = f2h(nv - h2f(hh));
  }
}

// ------------------------------------- final assembly
__global__ __launch_bounds__(256)
void k_final(const float* __restrict__ SLS, const float* __restrict__ GL,
             const float* __restrict__ xl, const float* __restrict__ dampen,
             const float* __restrict__ ltf_w, const float* __restrict__ ltf_b,
             float* __restrict__ out) {
  __shared__ float red[7][256];
  int b = blockIdx.x, t = blockIdx.y, tid = threadIdx.x;
  float acc[7] = {0, 0, 0, 0, 0, 0, 0};
  for (int d = tid; d < kD; d += 256) {
    int h = d >> 6;
    float df = sigf_acc(dampen[h]);
    float pwv = 0.0f, pw = 1.0f;
    for (int i = 0; i <= t; ++i) { pw *= df; pwv += pw; }
    float sm = fmaf(GL[b * kD + d], pwv, SLS[((long)(b * kD + d)) * kT + t]);
#pragma unroll
    for (int c = 0; c < 7; ++c) acc[c] = fmaf(ltf_w[c * kD + d], sm, acc[c]);
  }
#pragma unroll
  for (int c = 0; c < 7; ++c) red[c][tid] = acc[c];
  __syncthreads();
  for (int off = 128; off > 0; off >>= 1) {
    if (tid < off) {
#pragma unroll
      for (int c = 0; c < 7; ++c) red[c][tid] += red[c][tid + off];
    }
    __syncthreads();
  }
  if (tid < 7) {
    out[((long)b * kT + t) * kTF + tid] =
        xl[((long)b * kTF + tid) * kN + (kN - 1)] + red[tid][0] + ltf_b[tid];
  }
}

// ==================================================================== host
#define MG(EP, SK, grid, AH, AF, LDA, BH, LDB, SB, CV, CZH, CZL, LDC, SC, BIAS, KK) \
  do { if (useAW) k_mgemm<EP, 1, SK><<<grid, 256, 0, stream>>>( \
           (const void*)(AH), LDA, BH, LDB, SB, CV, CZH, CZL, LDC, SC, BIAS, KK); \
       else k_mgemm<EP, 0, SK><<<grid, 256, 0, stream>>>( \
           (const void*)(AF), LDA, BH, LDB, SB, CV, CZH, CZL, LDC, SC, BIAS, KK); } while (0)

extern "C" void kernel_launch(void* const* d_in, const int* in_sizes, int n_in,
                              void* d_out, int out_size, void* d_ws, size_t ws_size,
                              hipStream_t stream) {
  (void)in_sizes; (void)n_in; (void)out_size;
  const float* x      = (const float*)d_in[0];
  const float* emb_w  = (const float*)d_in[2];
  const float* emb_b  = (const float*)d_in[3];
  const float* mh_init= (const float*)d_in[4];
  const float* mh_al  = (const float*)d_in[5];
  const float* pin_w  = (const float*)d_in[6];
  const float* pin_b  = (const float*)d_in[7];
  const float* pout_w = (const float*)d_in[8];
  const float* pout_b = (const float*)d_in[9];
  const float* n1g    = (const float*)d_in[10];
  const float* n1b    = (const float*)d_in[11];
  const float* ff1w   = (const float*)d_in[12];
  const float* ff1b   = (const float*)d_in[13];
  const float* ff2w   = (const float*)d_in[14];
  const float* ff2b   = (const float*)d_in[15];
  const float* n2g    = (const float*)d_in[16];
  const float* n2b    = (const float*)d_in[17];
  const float* lv_al  = (const float*)d_in[18];
  const float* tg_w   = (const float*)d_in[19];
  const float* tg_b   = (const float*)d_in[20];
  const float* ts_w   = (const float*)d_in[21];
  const float* ts_b   = (const float*)d_in[22];
  const float* damp   = (const float*)d_in[23];
  const float* ltf_w  = (const float*)d_in[24];
  const float* ltf_b  = (const float*)d_in[25];
  float* out = (float*)d_out;

  float* ws = (float*)d_ws;
  size_t off = 0;
  auto alloc = [&](size_t n) { float* p = ws + off; off += n; return p; };
  float* bufA  = alloc(16777216);  // ls(fp16) / pin-out(fp16 rows) ; FF: Hb + bufB16
  float* ZhF   = alloc(8388608);   u16* Zh = (u16*)ZhF;   // z / zn hi (fp16)
  float* ZlF   = alloc(8388608);   u16* Zl = (u16*)ZlF;   // z / zn lo (fp16)
  float* sbuf  = alloc(229376);    // seasonal [B,7,N]
  float* gbuf  = alloc(229376);    // growth   [B,7,N]
  float* xT    = alloc(229376);    // x transposed
  float* xlA   = alloc(229376);
  float* xlB   = alloc(229376);
  float* SLS   = alloc(786432);    // sum of seasonal latents [:96]
  float* GL    = alloc(8192);      // sum of last growth latents
  float* GLlast= alloc(8192);      // per-layer scan last step
  float* tgp   = alloc(7168);
  float* gbc   = alloc(32);
  float* part  = alloc(524288);    // LN partial sums
  size_t base_need = off;
  float* wbuf  = alloc(1572864);   // pre-converted fp16 weights (optional)
  size_t full_need = off;
  if (ws_size < base_need * sizeof(float)) return;
  const bool useAW = (ws_size >= full_need * sizeof(float));

  u16* pinH  = (u16*)wbuf;           // 524288 (2 layers)
  u16* poutH = pinH + 524288;        // 524288
  u16* ff1H  = poutH + 524288;       // 1048576
  u16* ff2H  = ff1H + 1048576;       // 1048576

  u16*   lsb   = (u16*)bufA;                 // ls fp16 [b*512][2048]
  u16*   bufAu = (u16*)bufA;                 // pin-out/scan fp16 rows [b*512][4096]
  u16*   Hb    = (u16*)bufA;                 // FF hidden [b][2048][512] fp16
  u16*   bufB16 = (u16*)(bufA + 8388608);    // FF out fp16, 2 K-halves

  k_zero<<<dim3((794624 + 255) / 256), 256, 0, stream>>>(SLS, 794624); // SLS + GL
  k_precompute<<<dim3(14), 256, 0, stream>>>(tg_w, tg_b, pout_w, pout_b, tgp, gbc);
  if (useAW) {
    k_wcvt<<<dim3(2048), 256, 0, stream>>>(pin_w,  pinH,  524288);
    k_wcvt<<<dim3(2048), 256, 0, stream>>>(pout_w, poutH, 524288);
    k_wcvt<<<dim3(4096), 256, 0, stream>>>(ff1w,   ff1H,  1048576);
    k_wcvt<<<dim3(4096), 256, 0, stream>>>(ff2w,   ff2H,  1048576);
  }
  k_embed<<<dim3(8, 64, 16), 256, 0, stream>>>(x, emb_w, emb_b, Zh, Zl);
  k_transpose_x<<<dim3(896), 256, 0, stream>>>(x, xT);

  for (int l = 0; l < 2; ++l) {
    // ls = freq_attention(z); z -= ls; SLS += ls[:,:,:96]  (512-thread blocks)
    k_fft<<<dim3(kB * kD / 2), 512, 0, stream>>>(Zh, Zl, lsb, SLS);
    // seasonal = ls @ ts_w^T + ts_b  (ls fp16)
    k_gemm7v<2><<<dim3(32, 16), 256, 0, stream>>>(ts_w + l * 7 * kD, ts_b + l * 7, lsb, sbuf);
    // xp = pin x z   -> bufA fp16 rows [row][4096] (EP=3)
    MG(3, 0, dim3(16, 4, 16),
       pinH + l * 262144, pin_w + (long)l * 262144, 512,
       Zh, 2048, 1048576L, bufAu, nullptr, nullptr, 4096, 2097152L,
       pin_b + l * kD, 512);
    // EMA of first differences (fp16 in/out, in-place); GLlast
    k_scan_mhesa<<<dim3(kB * kD), 64, 0, stream>>>(bufAu, mh_al, mh_init, l, GLlast);
    k_gl<<<dim3(16, 8), 256, 0, stream>>>(GLlast, pout_w + (long)l * 262144, pout_b + l * kD, GL);
    k_gemm7v<1><<<dim3(32, 16), 256, 0, stream>>>(tgp + l * 7 * kD, gbc + l * 7, bufA, gbuf);
    // z -= pout x scan  (skipped at l=1: z is dead afterwards)
    if (l == 0) {
      MG(1, 0, dim3(16, 4, 16),
         poutH + l * 262144, pout_w + (long)l * 262144, 512,
         bufAu, 4096, 2097152L,
         nullptr, Zh, Zl, 2048, 1048576L, pout_b + l * kD, 512);
    }
    // level: xl = EMA_a(x - seasonal) + decay-accum(growth)
    k_scan_level<<<dim3(kB * kTF), 64, 0, stream>>>(
        (l == 0) ? xT : xlA, sbuf, gbuf, (l == 0) ? xlA : xlB, lv_al, l);
    if (l == 0) {
      // zn = LN1(z) in place (h/l)
      k_ln_part  <<<dim3(512, 8), 256, 0, stream>>>(Zh, Zl, nullptr, nullptr, part, 2048, 0);
      k_ln_apply2<<<dim3(512, 8), 256, 0, stream>>>(Zh, Zl, nullptr, nullptr, part, n1g, n1b, 2048, 0);
      // z = LN2(zn + sigmoid(zn@ff1^T+b1)@ff2^T+b2), 4 n-chunks of 512
      for (int nc = 0; nc < 4; ++nc) {
        int n0 = nc * 512;
        // H = sigmoid(ff1 x zn_chunk)  (fp16)
        MG(2, 0, dim3(4, 16, 16),
           ff1H, ff1w, 512,
           Zh + n0, 2048, 1048576L, Hb, nullptr, nullptr, 512, 1048576L,
           ff1b, 512);
        // ff = ff2 x H (fp16 out), split-K across 2 halves (bz = kh*16 + b)
        MG(3, 1, dim3(4, 4, 32),
           ff2H, ff2w, 2048,
           Hb, 512, 1048576L, bufB16, nullptr, nullptr, 512, 262144L,
           ff2b, 1024);
        k_ln_part  <<<dim3(128, 8), 256, 0, stream>>>(Zh, Zl, bufB16, bufB16 + 4194304, part, 512, n0);
        k_ln_apply2<<<dim3(128, 8), 256, 0, stream>>>(Zh, Zl, bufB16, bufB16 + 4194304, part, n2g, n2b, 512, n0);
      }
    }
  }
  k_final<<<dim3(16, 96), 256, 0, stream>>>(SLS, GL, xlB, damp, ltf_w, ltf_b, out);
}

// Round 16
// 943.265 us; speedup vs baseline: 1.0613x; 1.0613x over previous
//
#include <hip/hip_runtime.h>
#include <math.h>

// Problem constants (B=16, N=2048, TF=7, D=512, H=8, dh=64, Lyr=2, T=96)
constexpr int kB  = 16;
constexpr int kN  = 2048;
constexpr int kTF = 7;
constexpr int kD  = 512;
constexpr int kT  = 96;

typedef unsigned short u16;
typedef unsigned int   u32;
typedef unsigned long long u64;
typedef _Float16 f16;
typedef float f32x4 __attribute__((ext_vector_type(4)));
typedef short s16x4 __attribute__((ext_vector_type(4)));
typedef short s16x8 __attribute__((ext_vector_type(8)));
typedef _Float16 f16x8 __attribute__((ext_vector_type(8)));

__device__ __forceinline__ float sigf_fast(float x) { return 1.0f / (1.0f + __expf(-x)); }
__device__ __forceinline__ float sigf_acc (float x) { return 1.0f / (1.0f + expf(-x)); }

__device__ __forceinline__ u16 f2h(float f) {
  f16 h = (f16)f;
  return __builtin_bit_cast(u16, h);
}
__device__ __forceinline__ float h2f(u16 u) {
  return (float)__builtin_bit_cast(f16, u);
}

// async global->LDS, 16B per lane; lds base must be wave-uniform
__device__ __forceinline__ void gl_lds16(const u16* g, u16* l) {
  __builtin_amdgcn_global_load_lds(
      (const __attribute__((address_space(1))) u32*)g,
      (__attribute__((address_space(3))) u32*)l, 16, 0, 0);
}

// ---------------------------------------------------------------- utilities
__global__ void k_zero(float* p, int n) {
  int i = blockIdx.x * 256 + threadIdx.x;
  if (i < n) p[i] = 0.0f;
}

// fp32 -> fp16 convert (weights)
__global__ void k_wcvt(const float* __restrict__ w, u16* __restrict__ h, int n) {
  int i = blockIdx.x * 256 + threadIdx.x;
  if (i >= n) return;
  h[i] = f2h(w[i]);
}

// xT[b][c][n] = x[b][n][c]
__global__ void k_transpose_x(const float* __restrict__ x, float* __restrict__ xT) {
  int i = blockIdx.x * 256 + threadIdx.x;
  if (i >= kB * kTF * kN) return;
  int n = i & (kN - 1);
  int c = (i >> 11) % kTF;
  int b = i / (kTF * kN);
  xT[i] = x[((long)b * kN + n) * kTF + c];
}

// tgp[l][c][d] = sum_e tg_w[l][c][e] * pout_w[l][e][d];  gbc = tg_b + tg_w @ pout_b
__global__ void k_precompute(const float* __restrict__ tg_w, const float* __restrict__ tg_b,
                             const float* __restrict__ pout_w, const float* __restrict__ pout_b,
                             float* __restrict__ tgp, float* __restrict__ gbc) {
  int lc = blockIdx.x;            // l*7 + c
  int l = lc / 7;
  int tid = threadIdx.x;
  const float* tw = tg_w + lc * kD;
  const float* pw = pout_w + (long)l * kD * kD;
  for (int d = tid; d < kD; d += 256) {
    float acc = 0.0f;
    for (int e = 0; e < kD; ++e) acc = fmaf(tw[e], pw[(long)e * kD + d], acc);
    tgp[lc * kD + d] = acc;
  }
  if (tid == 0) {
    float acc = tg_b[lc];
    const float* pb = pout_b + l * kD;
    for (int e = 0; e < kD; ++e) acc = fmaf(tw[e], pb[e], acc);
    gbc[lc] = acc;
  }
}

// Conv1d(TF->D, k=3, pad=1) -> z as fp16 hi/lo
__global__ __launch_bounds__(256)
void k_embed(const float* __restrict__ x, const float* __restrict__ w,
             const float* __restrict__ bias, u16* __restrict__ Zh, u16* __restrict__ Zl) {
  int n = blockIdx.x * 256 + threadIdx.x;
  int d0 = blockIdx.y * 8;
  int b = blockIdx.z;
  const float* xb = x + (long)b * kN * kTF;
  float xr[21];
#pragma unroll
  for (int k = 0; k < 3; ++k) {
    int nn = n + k - 1;
    bool ok = (nn >= 0) && (nn < kN);
#pragma unroll
    for (int c = 0; c < 7; ++c) xr[k * 7 + c] = ok ? xb[nn * kTF + c] : 0.0f;
  }
  for (int dd = 0; dd < 8; ++dd) {
    int d = d0 + dd;
    const float* wd = w + d * 21;
    float acc = bias[d];
#pragma unroll
    for (int k = 0; k < 3; ++k)
#pragma unroll
      for (int c = 0; c < 7; ++c) acc = fmaf(xr[k * 7 + c], wd[c * 3 + k], acc);
    long idx = ((long)(b * kD + d)) * kN + n;
    u16 hh = f2h(acc);
    Zh[idx] = hh;
    Zl[idx] = f2h(acc - h2f(hh));
  }
}

// -------------------------------------------------- freq_attention
// Forward packed FFT (radix-4 passes) + top-4 SQUARED-amplitude mask
// (order-isomorphic to amplitude; sqrt removed); inverse replaced by DIRECT
// SYNTHESIS over the (typically 4) surviving bins per column.
#define AP(i) ((i) + ((i) >> 4))
#define TOP4_INS(key)                                              \
  do { u64 _k = (key);                                             \
    if (_k > t2) {                                                 \
      if (_k > t0)      { t3 = t2; t2 = t1; t1 = t0; t0 = _k; }    \
      else if (_k > t1) { t3 = t2; t2 = t1; t1 = _k; }             \
      else              { t3 = t2; t2 = _k; }                      \
    } else if (_k > t3) { t3 = _k; }                               \
  } while (0)

__global__ __launch_bounds__(256)
void k_fft(u16* __restrict__ zh, u16* __restrict__ zl,
           u16* __restrict__ lsb, float* __restrict__ SLS) {
  __shared__ float2 arr[2176];          // 2048 padded by i>>4
  __shared__ float2 twamp[1025];        // tw[0..1023] aliased with amp[0..2049]
  __shared__ u64   s_top[2][4][4];      // [col][wave][rank]
  __shared__ int   s_cnt[4];
  __shared__ float s_sv[2][4];
  __shared__ int   s_si[2][4];
  __shared__ float s_kth[2];
  __shared__ int   sKa[32], sKb[32];
  __shared__ float sCa[32], sSa[32], sCb[32], sSb[32];
  float* ampf = (float*)twamp;

  const int tid = threadIdx.x;
  const int b  = blockIdx.x >> 8;
  const int dp = blockIdx.x & 255;
  const long rowA = ((long)b * kD + dp * 2) * kN;
  const long rowB = rowA + kN;
  const int n0 = tid * 8;
  const int pbase = (int)(__brev((unsigned)tid) >> 24);   // brev8(tid)

  // ---- vectorized load + recombine + stash + bit-reversed scatter
  s16x8 vh = *(const s16x8*)&zh[rowA + n0];
  s16x8 vl = *(const s16x8*)&zl[rowA + n0];
  s16x8 wh = *(const s16x8*)&zh[rowB + n0];
  s16x8 wl = *(const s16x8*)&zl[rowB + n0];
  float2 stash[8];
#pragma unroll
  for (int j = 0; j < 8; ++j) {
    const int b3[8] = {0, 4, 2, 6, 1, 5, 3, 7};
    float va = h2f((u16)vh[j]) + h2f((u16)vl[j]);
    float vb = h2f((u16)wh[j]) + h2f((u16)wl[j]);
    stash[j] = make_float2(va, vb);
    int p = b3[j] * 256 + pbase;
    arr[AP(p)] = make_float2(va, vb);
  }
  for (int j = tid; j < 1024; j += 256) {
    float sw, cw;
    __sincosf(-6.283185307179586f * (float)j * (1.0f / 2048.0f), &sw, &cw);
    twamp[j] = make_float2(cw, sw);
  }
  __syncthreads();
  // ---- forward FFT: 5 radix-4 passes (stage pairs) + final radix-2
#pragma unroll
  for (int lh = 0; lh <= 8; lh += 2) {
    const int h = 1 << lh;
    const int sh1 = 10 - lh;
    const int sh2 = 9 - lh;
    for (int g = tid; g < 512; g += 256) {
      int pos = g & (h - 1);
      int i0 = ((g >> lh) << (lh + 2)) + pos;
      float2 a  = arr[AP(i0)];
      float2 bv = arr[AP(i0 + h)];
      float2 c  = arr[AP(i0 + 2 * h)];
      float2 d  = arr[AP(i0 + 3 * h)];
      float2 w1 = twamp[pos << sh1];
      float2 w2 = twamp[pos << sh2];
      float tbr = w1.x * bv.x - w1.y * bv.y, tbi = w1.x * bv.y + w1.y * bv.x;
      float tdr = w1.x * d.x  - w1.y * d.y,  tdi = w1.x * d.y  + w1.y * d.x;
      float a1r = a.x + tbr, a1i = a.y + tbi;
      float b1r = a.x - tbr, b1i = a.y - tbi;
      float c1r = c.x + tdr, c1i = c.y + tdi;
      float d1r = c.x - tdr, d1i = c.y - tdi;
      float tcr = w2.x * c1r - w2.y * c1i, tci = w2.x * c1i + w2.y * c1r;
      float ter = w2.y * d1r + w2.x * d1i;
      float tei = w2.y * d1i - w2.x * d1r;
      arr[AP(i0)]         = make_float2(a1r + tcr, a1i + tci);
      arr[AP(i0 + 2 * h)] = make_float2(a1r - tcr, a1i - tci);
      arr[AP(i0 + h)]     = make_float2(b1r + ter, b1i + tei);
      arr[AP(i0 + 3 * h)] = make_float2(b1r - ter, b1i - tei);
    }
    __syncthreads();
  }
  // final radix-2 stage (stride 1024)
  for (int j = tid; j < 1024; j += 256) {
    float2 w = twamp[j];
    float2 a  = arr[AP(j)];
    float2 bv = arr[AP(j + 1024)];
    float tr = w.x * bv.x - w.y * bv.y;
    float ti = w.x * bv.y + w.y * bv.x;
    arr[AP(j + 1024)] = make_float2(a.x - tr, a.y - ti);
    arr[AP(j)]        = make_float2(a.x + tr, a.y + ti);
  }
  __syncthreads();
  // ---- unpack SQUARED amplitudes (overwrites tw region)
  for (int k = tid; k <= 1024; k += 256) {
    float2 V0 = arr[AP(k)];
    float2 V1 = arr[AP((2048 - k) & 2047)];
    float ar = 0.5f * (V0.x + V1.x);
    float ai = 0.5f * (V0.y - V1.y);
    float br = 0.5f * (V0.y + V1.y);
    float bi = 0.5f * (V1.x - V0.x);
    ampf[k]        = ar * ar + ai * ai;
    ampf[1025 + k] = br * br + bi * bi;
  }
  __syncthreads();
  // ---- top-4 per column: single-pass sorted insert + wave shfl merge
#pragma unroll
  for (int col = 0; col < 2; ++col) {
    const float* A = ampf + col * 1025;
    u64 t0 = 0, t1 = 0, t2 = 0, t3 = 0;
    for (int k = tid; k <= 1024; k += 256) {
      u64 key = ((u64)__float_as_uint(A[k]) << 32) | (u32)k;
      TOP4_INS(key);
    }
#pragma unroll
    for (int off = 32; off > 0; off >>= 1) {
      u64 o0 = __shfl_xor(t0, off), o1 = __shfl_xor(t1, off);
      u64 o2 = __shfl_xor(t2, off), o3 = __shfl_xor(t3, off);
      TOP4_INS(o0); TOP4_INS(o1); TOP4_INS(o2); TOP4_INS(o3);
    }
    if ((tid & 63) == 0) {
      int w = tid >> 6;
      s_top[col][w][0] = t0; s_top[col][w][1] = t1;
      s_top[col][w][2] = t2; s_top[col][w][3] = t3;
    }
  }
  __syncthreads();
  if (tid < 2) {
    int col = tid;
    u64 t0 = s_top[col][0][0], t1 = s_top[col][0][1];
    u64 t2 = s_top[col][0][2], t3 = s_top[col][0][3];
    for (int w = 1; w < 4; ++w) {
#pragma unroll
      for (int r = 0; r < 4; ++r) { u64 key = s_top[col][w][r]; TOP4_INS(key); }
    }
    u64 tt[4] = {t0, t1, t2, t3};
#pragma unroll
    for (int r = 0; r < 4; ++r) {
      s_sv[col][r] = __uint_as_float((u32)(tt[r] >> 32));
      s_si[col][r] = (int)(tt[r] & 0xffffffffu);
    }
    s_kth[col] = __uint_as_float((u32)(tt[3] >> 32));
  }
  __syncthreads();
  const float kthA = s_kth[0], kthB = s_kth[1];
  // ---- survivor counts (deterministic)
  int cA = 0, cB = 0;
  for (int k = tid; k <= 1024; k += 256) {
    if (ampf[k] >= kthA) ++cA;
    if (ampf[1025 + k] >= kthB) ++cB;
  }
  int pc = cA | (cB << 16);
#pragma unroll
  for (int off = 32; off > 0; off >>= 1) pc += __shfl_xor(pc, off);
  if ((tid & 63) == 0) s_cnt[tid >> 6] = pc;
  __syncthreads();
  const int tot = s_cnt[0] + s_cnt[1] + s_cnt[2] + s_cnt[3];
  const int nA = tot & 0xffff, nB = tot >> 16;
  // ---- gather survivor coefficients (fast path: exactly the top-4)
  if (nA == 4) {
    if (tid < 4) {
      int k = s_si[0][tid];
      float2 V0 = arr[AP(k)];
      float2 V1 = arr[AP((2048 - k) & 2047)];
      float w = (k == 0 || k == 1024) ? 1.0f : 2.0f;
      sKa[tid] = k;
      sCa[tid] = w * 0.5f * (V0.x + V1.x);
      sSa[tid] = w * 0.5f * (V0.y - V1.y);
    }
  } else if (tid == 0) {
    int c = 0;
    for (int k = 0; k <= 1024 && c < 32; ++k) {
      if (ampf[k] >= kthA) {
        float2 V0 = arr[AP(k)];
        float2 V1 = arr[AP((2048 - k) & 2047)];
        float w = (k == 0 || k == 1024) ? 1.0f : 2.0f;
        sKa[c] = k;
        sCa[c] = w * 0.5f * (V0.x + V1.x);
        sSa[c] = w * 0.5f * (V0.y - V1.y);
        ++c;
      }
    }
  }
  if (nB == 4) {
    if (tid >= 64 && tid < 68) {
      int r = tid - 64;
      int k = s_si[1][r];
      float2 V0 = arr[AP(k)];
      float2 V1 = arr[AP((2048 - k) & 2047)];
      float w = (k == 0 || k == 1024) ? 1.0f : 2.0f;
      sKb[r] = k;
      sCb[r] = w * 0.5f * (V0.y + V1.y);
      sSb[r] = w * 0.5f * (V1.x - V0.x);
    }
  } else if (tid == 64) {
    int c = 0;
    for (int k = 0; k <= 1024 && c < 32; ++k) {
      if (ampf[1025 + k] >= kthB) {
        float2 V0 = arr[AP(k)];
        float2 V1 = arr[AP((2048 - k) & 2047)];
        float w = (k == 0 || k == 1024) ? 1.0f : 2.0f;
        sKb[c] = k;
        sCb[c] = w * 0.5f * (V0.y + V1.y);
        sSb[c] = w * 0.5f * (V1.x - V0.x);
        ++c;
      }
    }
  }
  __syncthreads();
  // ---- direct synthesis: ls[n] = (1/N) sum w_k (ar cos - ai sin), theta exact
  const int nAc = (nA < 32) ? nA : 32;
  const int nBc = (nB < 32) ? nB : 32;
  float synA[8] = {0, 0, 0, 0, 0, 0, 0, 0};
  float synB[8] = {0, 0, 0, 0, 0, 0, 0, 0};
  const float w2pi = 6.283185307179586f * (1.0f / 2048.0f);
  for (int s = 0; s < nAc; ++s) {
    int k = sKa[s];
    float cr = sCa[s], ci = sSa[s];
    float c0, s0, cs, ss;
    __sincosf(w2pi * (float)((k * n0) & 2047), &s0, &c0);
    __sincosf(w2pi * (float)k, &ss, &cs);
#pragma unroll
    for (int j = 0; j < 8; ++j) {
      synA[j] += cr * c0 - ci * s0;
      float nc = c0 * cs - s0 * ss;
      s0 = s0 * cs + c0 * ss;
      c0 = nc;
    }
  }
  for (int s = 0; s < nBc; ++s) {
    int k = sKb[s];
    float cr = sCb[s], ci = sSb[s];
    float c0, s0, cs, ss;
    __sincosf(w2pi * (float)((k * n0) & 2047), &s0, &c0);
    __sincosf(w2pi * (float)k, &ss, &cs);
#pragma unroll
    for (int j = 0; j < 8; ++j) {
      synB[j] += cr * c0 - ci * s0;
      float nc = c0 * cs - s0 * ss;
      s0 = s0 * cs + c0 * ss;
      c0 = nc;
    }
  }
  // ---- vectorized writeback: ls (fp16), z -= ls (h/l), SLS (fp32)
  const float inv = 1.0f / 2048.0f;
  s16x8 oh_a, ol_a, oh_b, ol_b, os_a, os_b;
  float la8[8], lb8[8];
#pragma unroll
  for (int j = 0; j < 8; ++j) {
    float la = synA[j] * inv, lb = synB[j] * inv;
    la8[j] = la; lb8[j] = lb;
    os_a[j] = (short)f2h(la);
    os_b[j] = (short)f2h(lb);
    float za = stash[j].x - la, zb = stash[j].y - lb;
    u16 ha = f2h(za), hb = f2h(zb);
    oh_a[j] = (short)ha; ol_a[j] = (short)f2h(za - h2f(ha));
    oh_b[j] = (short)hb; ol_b[j] = (short)f2h(zb - h2f(hb));
  }
  *(s16x8*)&lsb[rowA + n0] = os_a;
  *(s16x8*)&lsb[rowB + n0] = os_b;
  *(s16x8*)&zh[rowA + n0] = oh_a;
  *(s16x8*)&zl[rowA + n0] = ol_a;
  *(s16x8*)&zh[rowB + n0] = oh_b;
  *(s16x8*)&zl[rowB + n0] = ol_b;
  if (n0 < kT) {
    float* s0p = &SLS[((long)(b * kD + dp * 2)) * kT + n0];
    float* s1p = &SLS[((long)(b * kD + dp * 2 + 1)) * kT + n0];
#pragma unroll
    for (int j = 0; j < 8; ++j) { s0p[j] += la8[j]; s1p[j] += lb8[j]; }
  }
}

// ==================================================================== MFMA GEMM
// C[M,N] = W[M,K] x Act[K,N] per batch. FP16 single-product MFMA.
// 256 threads, 4 waves (2x2), tile 128x128, BK=32, 64-K macro-iterations.
// CROSS-ITERATION 2-PHASE PIPELINE: 2 LDS buffer sets (72 KB, 2 blk/CU);
// stage(t+1) issued BEFORE compute(t); ONE barrier per 64-K iteration.
// AW=1: A pre-converted fp16 (gl_lds16 + XOR-swizzled source).
// EP: 0 = fp32 store; 1 = z(h/l) -= (acc+bias); 2 = fp16 sigmoid; 3 = fp16 store.
// SK=1: blockIdx.z encodes (khalf = z>>4, batch = z&15), K-half offset 1024.
template<int EP, int AW, int SK>
__global__ __launch_bounds__(256)
void k_mgemm(const void* __restrict__ Ag, int lda,
             const u16* __restrict__ Bh, int ldb, long strideB,
             void* __restrict__ Cgv, u16* __restrict__ Czh, u16* __restrict__ Czl,
             int ldc, long strideC,
             const float* __restrict__ bias, int K) {
  __shared__ u16 sA[2][2][128 * 32];
  __shared__ u16 sB[2][2][128 * 40];

  const int tid = threadIdx.x;
  const int bx = blockIdx.x, by = blockIdx.y, bz = blockIdx.z;
  const int batch = SK ? (bz & 15) : bz;
  const int kofs  = SK ? ((bz >> 4) * 1024) : 0;
  const int lane = tid & 63;
  const int wid  = tid >> 6;
  const int wm = wid >> 1, wn = wid & 1;
  const int l15 = lane & 15, lk = lane >> 4;

  const u16* Bbase = Bh + (size_t)batch * strideB + (size_t)kofs * ldb + bx * 128;
  const u16* Abase = (const u16*)Ag + kofs;
  const float* Afb = (const float*)Ag + kofs;

  f32x4 acc[4][4];
#pragma unroll
  for (int i = 0; i < 4; ++i)
#pragma unroll
    for (int j = 0; j < 4; ++j) acc[i][j] = (f32x4)(0.0f);

  const int kq = tid >> 5, nb = tid & 31, n0 = nb * 4;
  s16x4 br[2][4];

#define STAGEA(bf, half, k0)                                                  \
  do {                                                                        \
    if (AW) {                                                                 \
      _Pragma("unroll")                                                       \
      for (int c = 0; c < 2; ++c) {                                           \
        int L = wid * 128 + c * 64 + lane;                                    \
        int m = L >> 2, s = L & 3;                                            \
        int klog = ((s ^ ((m >> 1) & 3)) << 3);                               \
        size_t srco = (size_t)(by * 128 + m) * lda + (k0) + klog;             \
        gl_lds16(Abase + srco,                                                \
                 &sA[bf][half][(size_t)(wid * 128 + c * 64) * 8]);            \
      }                                                                       \
    } else {                                                                  \
      _Pragma("unroll")                                                       \
      for (int it = 0; it < 2; ++it) {                                        \
        int m = it * 64 + (tid >> 2), s = tid & 3;                            \
        const float* ap = Afb + (size_t)(by * 128 + m) * lda + (k0) + s * 8;  \
        f32x4 v0 = *(const f32x4*)ap;                                         \
        f32x4 v1 = *(const f32x4*)(ap + 4);                                   \
        float fv[8] = {v0[0], v0[1], v0[2], v0[3],                            \
                       v1[0], v1[1], v1[2], v1[3]};                           \
        u32 hh[8];                                                            \
        _Pragma("unroll")                                                     \
        for (int e = 0; e < 8; ++e) hh[e] = f2h(fv[e]);                       \
        int so = ((s ^ ((m >> 1) & 3)) << 3);                                 \
        uint4 vp = make_uint4(hh[0] | (hh[1] << 16), hh[2] | (hh[3] << 16),   \
                              hh[4] | (hh[5] << 16), hh[6] | (hh[7] << 16));  \
        *(uint4*)&sA[bf][half][m * 32 + so] = vp;                             \
      }                                                                       \
    }                                                                         \
  } while (0)

#define LOADB(half, k0)                                                       \
  do {                                                                        \
    const u16* bp = Bbase + (size_t)((k0) + kq * 4) * ldb + n0;               \
    br[half][0] = *(const s16x4*)bp;                                          \
    br[half][1] = *(const s16x4*)(bp + ldb);                                  \
    br[half][2] = *(const s16x4*)(bp + 2 * (size_t)ldb);                      \
    br[half][3] = *(const s16x4*)(bp + 3 * (size_t)ldb);                      \
  } while (0)

#define WRITEB(bf, half)                                                      \
  do {                                                                        \
    _Pragma("unroll")                                                         \
    for (int i = 0; i < 4; ++i) {                                             \
      int n = n0 + i;                                                         \
      int so = (((kq >> 1) ^ ((n >> 2) & 3)) << 3) + (kq & 1) * 4;            \
      *(uint2*)&sB[bf][half][n * 40 + so] = make_uint2(                       \
          (u32)(u16)br[half][0][i] | ((u32)(u16)br[half][1][i] << 16),        \
          (u32)(u16)br[half][2][i] | ((u32)(u16)br[half][3][i] << 16));       \
    }                                                                         \
  } while (0)

#define COMPUTE(bf, half)                                                     \
  do {                                                                        \
    f16x8 bhf[4];                                                             \
    _Pragma("unroll")                                                         \
    for (int ni = 0; ni < 4; ++ni) {                                          \
      int row = wn * 64 + ni * 16 + l15;                                      \
      int so = ((lk ^ ((row >> 2) & 3)) << 3);                                \
      bhf[ni] = *(const f16x8*)&sB[bf][half][row * 40 + so];                  \
    }                                                                         \
    _Pragma("unroll")                                                         \
    for (int mi = 0; mi < 4; ++mi) {                                          \
      int row = wm * 64 + mi * 16 + l15;                                      \
      int so = ((lk ^ ((row >> 1) & 3)) << 3);                                \
      f16x8 ah = *(const f16x8*)&sA[bf][half][row * 32 + so];                 \
      _Pragma("unroll")                                                       \
      for (int ni = 0; ni < 4; ++ni)                                          \
        acc[mi][ni] = __builtin_amdgcn_mfma_f32_16x16x32_f16(                 \
            ah, bhf[ni], acc[mi][ni], 0, 0, 0);                               \
    }                                                                         \
  } while (0)

  // prologue: stage iteration 0 into set 0
  STAGEA(0, 0, 0);
  STAGEA(0, 1, 32);
  LOADB(0, 0);
  LOADB(1, 32);
  WRITEB(0, 0);
  WRITEB(0, 1);
  __syncthreads();

  const int NT = K >> 6;
  for (int t = 0; t < NT; ++t) {
    const int cur = t & 1, nxt = cur ^ 1;
    const int kn = (t + 1) * 64;
    if (t + 1 < NT) {
      STAGEA(nxt, 0, kn);          // gl_lds in flight during compute
      STAGEA(nxt, 1, kn + 32);
      LOADB(0, kn);                // B loads in flight during compute
      LOADB(1, kn + 32);
    }
    COMPUTE(cur, 0);
    COMPUTE(cur, 1);
    if (t + 1 < NT) {
      WRITEB(nxt, 0);
      WRITEB(nxt, 1);
    }
    __syncthreads();               // single drain+barrier per 64-K iteration
  }
#undef STAGEA
#undef LOADB
#undef WRITEB
#undef COMPUTE

  // ---- epilogue (C/D: col = lane&15, row = (lane>>4)*4 + reg)
  const float bmul = (SK && (bz >> 4)) ? 0.0f : 1.0f;
  float* Cf = (float*)Cgv + (size_t)bz * strideC;
  u16*   Ch = (u16*)Cgv + (size_t)bz * strideC;
  u16*   Zph = Czh ? Czh + (size_t)bz * strideC : nullptr;
  u16*   Zpl = Czl ? Czl + (size_t)bz * strideC : nullptr;
#pragma unroll
  for (int mi = 0; mi < 4; ++mi) {
    int row0 = by * 128 + wm * 64 + mi * 16 + lk * 4;
    float bs[4];
#pragma unroll
    for (int r = 0; r < 4; ++r) bs[r] = bias[row0 + r] * bmul;
#pragma unroll
    for (int ni = 0; ni < 4; ++ni) {
      int col = bx * 128 + wn * 64 + ni * 16 + l15;
#pragma unroll
      for (int r = 0; r < 4; ++r) {
        float v = acc[mi][ni][r] + bs[r];
        size_t off = (size_t)(row0 + r) * ldc + col;
        if (EP == 0) {
          Cf[off] = v;
        } else if (EP == 1) {
          float zv = h2f(Zph[off]) + h2f(Zpl[off]);
          float nv = zv - v;
          u16 hh = f2h(nv);
          Zph[off] = hh;
          Zpl[off] = f2h(nv - h2f(hh));
        } else if (EP == 2) {
          Ch[off] = f2h(sigf_fast(v));
        } else {
          Ch[off] = f2h(v);
        }
      }
    }
  }
}

// ------------------------------------- 7-channel GEMM, 4-way d-split
// HL=1: fp16 rows [b*512][4096] (h at offset 0); HL=2: fp16 [b*512][2048]
template<int HL>
__global__ __launch_bounds__(256)
void k_gemm7v(const float* __restrict__ W, const float* __restrict__ bias,
              const void* __restrict__ in, float* __restrict__ out) {
  __shared__ float Ws[7 * kD];
  __shared__ float red[4][7][64];
  int tid = threadIdx.x;
  for (int i = tid; i < 7 * kD; i += 256) Ws[i] = W[i];
  __syncthreads();
  int nl = tid & 63, dg = tid >> 6;
  int n = blockIdx.x * 64 + nl;
  int b = blockIdx.y;
  float acc[7] = {0, 0, 0, 0, 0, 0, 0};
  if (HL == 1) {
    const u16* ph = (const u16*)in + ((long)b * kD) * 4096 + n;
    for (int d = dg * 128; d < dg * 128 + 128; ++d) {
      float v = h2f(ph[(long)d * 4096]);
#pragma unroll
      for (int c = 0; c < 7; ++c) acc[c] = fmaf(Ws[c * kD + d], v, acc[c]);
    }
  } else {
    const u16* ph = (const u16*)in + ((long)b * kD) * 2048 + n;
    for (int d = dg * 128; d < dg * 128 + 128; ++d) {
      float v = h2f(ph[(long)d * 2048]);
#pragma unroll
      for (int c = 0; c < 7; ++c) acc[c] = fmaf(Ws[c * kD + d], v, acc[c]);
    }
  }
#pragma unroll
  for (int c = 0; c < 7; ++c) red[dg][c][nl] = acc[c];
  __syncthreads();
  if (dg == 0) {
#pragma unroll
    for (int c = 0; c < 7; ++c) {
      float t = red[0][c][nl] + red[1][c][nl] + red[2][c][nl] + red[3][c][nl] + bias[c];
      out[((long)b * kTF + c) * kN + n] = t;
    }
  }
}

// ------------------------------------- mhesa EMA-of-diffs scan
// in/out: u16 rows [row][4096], fp16 h in first 2048 slots (in-place); + GLlast
__global__ __launch_bounds__(64)
void k_scan_mhesa(u16* __restrict__ buf, const float* __restrict__ alpha_raw,
                  const float* __restrict__ init_st, int layer, float* __restrict__ GLlast) {
  int row = blockIdx.x;                // b*512 + d
  int d = row & (kD - 1);
  int h = d >> 6, j = d & 63;
  int lane = threadIdx.x;
  float a = sigf_acc(alpha_raw[layer * 8 + h]);
  float c = 1.0f - a;
  float init = init_st[(layer * 8 + h) * 64 + j];
  long base = (long)row * 4096 + lane * 32;
  float x[32];
  {
    s16x8 r0 = *(const s16x8*)&buf[base];
    s16x8 r1 = *(const s16x8*)&buf[base + 8];
    s16x8 r2 = *(const s16x8*)&buf[base + 16];
    s16x8 r3 = *(const s16x8*)&buf[base + 24];
#pragma unroll
    for (int m = 0; m < 8; ++m) {
      x[m]      = h2f((u16)r0[m]);
      x[m + 8]  = h2f((u16)r1[m]);
      x[m + 16] = h2f((u16)r2[m]);
      x[m + 24] = h2f((u16)r3[m]);
    }
  }
  float prev = __shfl_up(x[31], 1);
  if (lane == 0) prev = init;
  float p[32];
  float pp = 0.0f;
#pragma unroll
  for (int m = 0; m < 32; ++m) {
    float u = a * (x[m] - prev);
    prev = x[m];
    pp = fmaf(c, pp, u);
    p[m] = pp;
  }
  float c2 = c * c, c4 = c2 * c2, c8 = c4 * c4, c16 = c8 * c8;
  float C_ = c16 * c16, U_ = pp;
#pragma unroll
  for (int off = 1; off < 64; off <<= 1) {
    float Cp = __shfl_up(C_, off);
    float Up = __shfl_up(U_, off);
    if (lane >= off) { U_ = fmaf(C_, Up, U_); C_ = C_ * Cp; }
  }
  float Uex = __shfl_up(U_, 1);
  float Cex = __shfl_up(C_, 1);
  if (lane == 0) { Uex = 0.0f; Cex = 1.0f; }
  float yin = fmaf(Cex, init, Uex);
  float pw = c;
  float ylast = 0.0f;
  s16x8 o[4];
#pragma unroll
  for (int m = 0; m < 32; ++m) {
    float y = fmaf(pw, yin, p[m]);
    o[m >> 3][m & 7] = (short)f2h(y);
    pw *= c;
    ylast = y;
  }
  *(s16x8*)&buf[base]      = o[0];
  *(s16x8*)&buf[base + 8]  = o[1];
  *(s16x8*)&buf[base + 16] = o[2];
  *(s16x8*)&buf[base + 24] = o[3];
  if (lane == 63) GLlast[row] = ylast;
}

// ------------------------------------- level scan: y = (1-a)y + a(x-s) + g, init 0
__global__ __launch_bounds__(64)
void k_scan_level(const float* __restrict__ xin, const float* __restrict__ sea,
                  const float* __restrict__ gro, float* __restrict__ xout,
                  const float* __restrict__ lv_alpha, int layer) {
  int row = blockIdx.x;                // b*7 + c
  int lane = threadIdx.x;
  float a = sigf_acc(lv_alpha[layer]);
  float c = 1.0f - a;
  long base = (long)row * kN + lane * 32;
  float p[32];
  float pp = 0.0f;
#pragma unroll
  for (int m = 0; m < 32; ++m) {
    float u = fmaf(a, xin[base + m] - sea[base + m], gro[base + m]);
    pp = fmaf(c, pp, u);
    p[m] = pp;
  }
  float c2 = c * c, c4 = c2 * c2, c8 = c4 * c4, c16 = c8 * c8;
  float C_ = c16 * c16, U_ = pp;
#pragma unroll
  for (int off = 1; off < 64; off <<= 1) {
    float Cp = __shfl_up(C_, off);
    float Up = __shfl_up(U_, off);
    if (lane >= off) { U_ = fmaf(C_, Up, U_); C_ = C_ * Cp; }
  }
  float Uex = __shfl_up(U_, 1);
  if (lane == 0) Uex = 0.0f;
  float yin = Uex;
  float pw = c;
#pragma unroll
  for (int m = 0; m < 32; ++m) {
    xout[base + m] = fmaf(pw, yin, p[m]);
    pw *= c;
  }
}

// ------------------------------------- GL[b,e] += pout(scan_last); grid(16,8)
__global__ __launch_bounds__(256)
void k_gl(const float* __restrict__ GLlast, const float* __restrict__ pw,
          const float* __restrict__ pb, float* __restrict__ GL) {
  __shared__ float sl[kD];
  __shared__ float red[4][64];
  int b = blockIdx.x, tid = threadIdx.x;
  for (int d = tid; d < kD; d += 256) sl[d] = GLlast[b * kD + d];
  __syncthreads();
  int e0 = blockIdx.y * 64;
  int el = tid & 63, kg = tid >> 6;
  float acc = 0.0f;
  const float* pwe = pw + (long)(e0 + el) * kD + kg * 128;
  const float* slp = sl + kg * 128;
  for (int d = 0; d < 128; ++d) acc = fmaf(pwe[d], slp[d], acc);
  red[kg][el] = acc;
  __syncthreads();
  if (kg == 0) {
    float t = red[0][el] + red[1][el] + red[2][el] + red[3][el] + pb[e0 + el];
    GL[b * kD + e0 + el] += t;
  }
}

// ------------------------------------- LayerNorm (z fp16 hi/lo, add fp16), 2-stage
__global__ __launch_bounds__(256)
void k_ln_part(const u16* __restrict__ zh, const u16* __restrict__ zl,
               const u16* __restrict__ a0, const u16* __restrict__ a1,
               float* __restrict__ part, int ncols, int n0) {
  __shared__ float sh1[4][64], sh2[4][64];
  int nperb = ncols >> 6;
  int b = blockIdx.x / nperb, nblk = blockIdx.x % nperb;
  int nl = threadIdx.x & 63;
  int dg = threadIdx.x >> 6;
  int n = nblk * 64 + nl;
  int d0 = blockIdx.y * 64 + dg * 16;
  const u16* zp = zh + (long)b * kD * kN + n0 + n;
  const u16* zq = zl + (long)b * kD * kN + n0 + n;
  const u16* p0 = a0 ? a0 + (long)b * kD * ncols + n : nullptr;
  const u16* p1 = a1 ? a1 + (long)b * kD * ncols + n : nullptr;
  float s1 = 0.0f, s2 = 0.0f;
#pragma unroll
  for (int dd = 0; dd < 16; ++dd) {
    int d = d0 + dd;
    float v = h2f(zp[(long)d * kN]) + h2f(zq[(long)d * kN]);
    if (p0) v += h2f(p0[(long)d * ncols]);
    if (p1) v += h2f(p1[(long)d * ncols]);
    s1 += v; s2 += v * v;
  }
  sh1[dg][nl] = s1; sh2[dg][nl] = s2;
  __syncthreads();
  if (dg == 0) {
    float t1 = sh1[0][nl] + sh1[1][nl] + sh1[2][nl] + sh1[3][nl];
    float t2 = sh2[0][nl] + sh2[1][nl] + sh2[2][nl] + sh2[3][nl];
    long pi = ((long)blockIdx.y * kB * ncols + (long)b * ncols + n) * 2;
    part[pi] = t1; part[pi + 1] = t2;
  }
}

__global__ __launch_bounds__(256)
void k_ln_apply2(u16* __restrict__ zh, u16* __restrict__ zl,
                 const u16* __restrict__ a0, const u16* __restrict__ a1,
                 const float* __restrict__ part,
                 const float* __restrict__ g, const float* __restrict__ bb,
                 int ncols, int n0) {
  __shared__ float smu[64], srs[64];
  int nperb = ncols >> 6;
  int b = blockIdx.x / nperb, nblk = blockIdx.x % nperb;
  int nl = threadIdx.x & 63;
  int dg = threadIdx.x >> 6;
  int n = nblk * 64 + nl;
  if (dg == 0) {
    float t1 = 0.0f, t2 = 0.0f;
#pragma unroll
    for (int s = 0; s < 8; ++s) {
      long pi = ((long)s * kB * ncols + (long)b * ncols + n) * 2;
      t1 += part[pi]; t2 += part[pi + 1];
    }
    float m = t1 * (1.0f / kD);
    float var = t2 * (1.0f / kD) - m * m;
    smu[nl] = m;
    srs[nl] = rsqrtf(var + 1e-5f);
  }
  __syncthreads();
  float m = smu[nl], r = srs[nl];
  int d0 = blockIdx.y * 64 + dg * 16;
  u16* zp = zh + (long)b * kD * kN + n0 + n;
  u16* zq = zl + (long)b * kD * kN + n0 + n;
  const u16* p0 = a0 ? a0 + (long)b * kD * ncols + n : nullptr;
  const u16* p1 = a1 ? a1 + (long)b * kD * ncols + n : nullptr;
#pragma unroll
  for (int dd = 0; dd < 16; ++dd) {
    int d = d0 + dd;
    float v = h2f(zp[(long)d * kN]) + h2f(zq[(long)d * kN]);
    if (p0) v += h2f(p0[(long)d * ncols]);
    if (p1) v += h2f(p1[(long)d * ncols]);
    float nv = (v - m) * r * g[d] + bb[d];
    u16 hh = f2h(nv);
    zp[(long)d * kN] = hh;
    zq[(long)d * kN] = f2h(nv - h2f(hh));
  }
}

// ------------------------------------- final assembly
__global__ __launch_bounds__(256)
void k_final(const float* __restrict__ SLS, const float* __restrict__ GL,
             const float* __restrict__ xl, const float* __restrict__ dampen,
             const float* __restrict__ ltf_w, const float* __restrict__ ltf_b,
             float* __restrict__ out) {
  __shared__ float red[7][256];
  int b = blockIdx.x, t = blockIdx.y, tid = threadIdx.x;
  float acc[7] = {0, 0, 0, 0, 0, 0, 0};
  for (int d = tid; d < kD; d += 256) {
    int h = d >> 6;
    float df = sigf_acc(dampen[h]);
    float pwv = 0.0f, pw = 1.0f;
    for (int i = 0; i <= t; ++i) { pw *= df; pwv += pw; }
    float sm = fmaf(GL[b * kD + d], pwv, SLS[((long)(b * kD + d)) * kT + t]);
#pragma unroll
    for (int c = 0; c < 7; ++c) acc[c] = fmaf(ltf_w[c * kD + d], sm, acc[c]);
  }
#pragma unroll
  for (int c = 0; c < 7; ++c) red[c][tid] = acc[c];
  __syncthreads();
  for (int off = 128; off > 0; off >>= 1) {
    if (tid < off) {
#pragma unroll
      for (int c = 0; c < 7; ++c) red[c][tid] += red[c][tid + off];
    }
    __syncthreads();
  }
  if (tid < 7) {
    out[((long)b * kT + t) * kTF + tid] =
        xl[((long)b * kTF + tid) * kN + (kN - 1)] + red[tid][0] + ltf_b[tid];
  }
}

// ==================================================================== host
#define MG(EP, SK, grid, AH, AF, LDA, BH, LDB, SB, CV, CZH, CZL, LDC, SC, BIAS, KK) \
  do { if (useAW) k_mgemm<EP, 1, SK><<<grid, 256, 0, stream>>>( \
           (const void*)(AH), LDA, BH, LDB, SB, CV, CZH, CZL, LDC, SC, BIAS, KK); \
       else k_mgemm<EP, 0, SK><<<grid, 256, 0, stream>>>( \
           (const void*)(AF), LDA, BH, LDB, SB, CV, CZH, CZL, LDC, SC, BIAS, KK); } while (0)

extern "C" void kernel_launch(void* const* d_in, const int* in_sizes, int n_in,
                              void* d_out, int out_size, void* d_ws, size_t ws_size,
                              hipStream_t stream) {
  (void)in_sizes; (void)n_in; (void)out_size;
  const float* x      = (const float*)d_in[0];
  const float* emb_w  = (const float*)d_in[2];
  const float* emb_b  = (const float*)d_in[3];
  const float* mh_init= (const float*)d_in[4];
  const float* mh_al  = (const float*)d_in[5];
  const float* pin_w  = (const float*)d_in[6];
  const float* pin_b  = (const float*)d_in[7];
  const float* pout_w = (const float*)d_in[8];
  const float* pout_b = (const float*)d_in[9];
  const float* n1g    = (const float*)d_in[10];
  const float* n1b    = (const float*)d_in[11];
  const float* ff1w   = (const float*)d_in[12];
  const float* ff1b   = (const float*)d_in[13];
  const float* ff2w   = (const float*)d_in[14];
  const float* ff2b   = (const float*)d_in[15];
  const float* n2g    = (const float*)d_in[16];
  const float* n2b    = (const float*)d_in[17];
  const float* lv_al  = (const float*)d_in[18];
  const float* tg_w   = (const float*)d_in[19];
  const float* tg_b   = (const float*)d_in[20];
  const float* ts_w   = (const float*)d_in[21];
  const float* ts_b   = (const float*)d_in[22];
  const float* damp   = (const float*)d_in[23];
  const float* ltf_w  = (const float*)d_in[24];
  const float* ltf_b  = (const float*)d_in[25];
  float* out = (float*)d_out;

  float* ws = (float*)d_ws;
  size_t off = 0;
  auto alloc = [&](size_t n) { float* p = ws + off; off += n; return p; };
  float* bufA  = alloc(16777216);  // ls(fp16) / pin-out(fp16 rows) ; FF: Hb + bufB16
  float* ZhF   = alloc(8388608);   u16* Zh = (u16*)ZhF;   // z / zn hi (fp16)
  float* ZlF   = alloc(8388608);   u16* Zl = (u16*)ZlF;   // z / zn lo (fp16)
  float* sbuf  = alloc(229376);    // seasonal [B,7,N]
  float* gbuf  = alloc(229376);    // growth   [B,7,N]
  float* xT    = alloc(229376);    // x transposed
  float* xlA   = alloc(229376);
  float* xlB   = alloc(229376);
  float* SLS   = alloc(786432);    // sum of seasonal latents [:96]
  float* GL    = alloc(8192);      // sum of last growth latents
  float* GLlast= alloc(8192);      // per-layer scan last step
  float* tgp   = alloc(7168);
  float* gbc   = alloc(32);
  float* part  = alloc(524288);    // LN partial sums
  size_t base_need = off;
  float* wbuf  = alloc(1572864);   // pre-converted fp16 weights (optional)
  size_t full_need = off;
  if (ws_size < base_need * sizeof(float)) return;
  const bool useAW = (ws_size >= full_need * sizeof(float));

  u16* pinH  = (u16*)wbuf;           // 524288 (2 layers)
  u16* poutH = pinH + 524288;        // 524288
  u16* ff1H  = poutH + 524288;       // 1048576
  u16* ff2H  = ff1H + 1048576;       // 1048576

  u16*   lsb   = (u16*)bufA;                 // ls fp16 [b*512][2048]
  u16*   bufAu = (u16*)bufA;                 // pin-out/scan fp16 rows [b*512][4096]
  u16*   Hb    = (u16*)bufA;                 // FF hidden [b][2048][512] fp16
  u16*   bufB16 = (u16*)(bufA + 8388608);    // FF out fp16, 2 K-halves

  k_zero<<<dim3((794624 + 255) / 256), 256, 0, stream>>>(SLS, 794624); // SLS + GL
  k_precompute<<<dim3(14), 256, 0, stream>>>(tg_w, tg_b, pout_w, pout_b, tgp, gbc);
  if (useAW) {
    k_wcvt<<<dim3(2048), 256, 0, stream>>>(pin_w,  pinH,  524288);
    k_wcvt<<<dim3(2048), 256, 0, stream>>>(pout_w, poutH, 524288);
    k_wcvt<<<dim3(4096), 256, 0, stream>>>(ff1w,   ff1H,  1048576);
    k_wcvt<<<dim3(4096), 256, 0, stream>>>(ff2w,   ff2H,  1048576);
  }
  k_embed<<<dim3(8, 64, 16), 256, 0, stream>>>(x, emb_w, emb_b, Zh, Zl);
  k_transpose_x<<<dim3(896), 256, 0, stream>>>(x, xT);

  for (int l = 0; l < 2; ++l) {
    // ls = freq_attention(z); z -= ls; SLS += ls[:,:,:96]
    k_fft<<<dim3(kB * kD / 2), 256, 0, stream>>>(Zh, Zl, lsb, SLS);
    // seasonal = ls @ ts_w^T + ts_b  (ls fp16)
    k_gemm7v<2><<<dim3(32, 16), 256, 0, stream>>>(ts_w + l * 7 * kD, ts_b + l * 7, lsb, sbuf);
    // xp = pin x z   -> bufA fp16 rows [row][4096] (EP=3)
    MG(3, 0, dim3(16, 4, 16),
       pinH + l * 262144, pin_w + (long)l * 262144, 512,
       Zh, 2048, 1048576L, bufAu, nullptr, nullptr, 4096, 2097152L,
       pin_b + l * kD, 512);
    // EMA of first differences (fp16 in/out, in-place); GLlast
    k_scan_mhesa<<<dim3(kB * kD), 64, 0, stream>>>(bufAu, mh_al, mh_init, l, GLlast);
    k_gl<<<dim3(16, 8), 256, 0, stream>>>(GLlast, pout_w + (long)l * 262144, pout_b + l * kD, GL);
    k_gemm7v<1><<<dim3(32, 16), 256, 0, stream>>>(tgp + l * 7 * kD, gbc + l * 7, bufA, gbuf);
    // z -= pout x scan  (skipped at l=1: z is dead afterwards)
    if (l == 0) {
      MG(1, 0, dim3(16, 4, 16),
         poutH + l * 262144, pout_w + (long)l * 262144, 512,
         bufAu, 4096, 2097152L,
         nullptr, Zh, Zl, 2048, 1048576L, pout_b + l * kD, 512);
    }
    // level: xl = EMA_a(x - seasonal) + decay-accum(growth)
    k_scan_level<<<dim3(kB * kTF), 64, 0, stream>>>(
        (l == 0) ? xT : xlA, sbuf, gbuf, (l == 0) ? xlA : xlB, lv_al, l);
    if (l == 0) {
      // zn = LN1(z) in place (h/l)
      k_ln_part  <<<dim3(512, 8), 256, 0, stream>>>(Zh, Zl, nullptr, nullptr, part, 2048, 0);
      k_ln_apply2<<<dim3(512, 8), 256, 0, stream>>>(Zh, Zl, nullptr, nullptr, part, n1g, n1b, 2048, 0);
      // z = LN2(zn + sigmoid(zn@ff1^T+b1)@ff2^T+b2), 4 n-chunks of 512
      for (int nc = 0; nc < 4; ++nc) {
        int n0 = nc * 512;
        // H = sigmoid(ff1 x zn_chunk)  (fp16)
        MG(2, 0, dim3(4, 16, 16),
           ff1H, ff1w, 512,
           Zh + n0, 2048, 1048576L, Hb, nullptr, nullptr, 512, 1048576L,
           ff1b, 512);
        // ff = ff2 x H (fp16 out), split-K across 2 halves (bz = kh*16 + b)
        MG(3, 1, dim3(4, 4, 32),
           ff2H, ff2w, 2048,
           Hb, 512, 1048576L, bufB16, nullptr, nullptr, 512, 262144L,
           ff2b, 1024);
        k_ln_part  <<<dim3(128, 8), 256, 0, stream>>>(Zh, Zl, bufB16, bufB16 + 4194304, part, 512, n0);
        k_ln_apply2<<<dim3(128, 8), 256, 0, stream>>>(Zh, Zl, bufB16, bufB16 + 4194304, part, n2g, n2b, 512, n0);
      }
    }
  }
  k_final<<<dim3(16, 96), 256, 0, stream>>>(SLS, GL, xlB, damp, ltf_w, ltf_b, out);
}